// Round 1
// baseline (129.432 us; speedup 1.0000x reference)
//
#include <hip/hip_runtime.h>

#define N      8192   // 8*32*32
#define NCLS   8
#define NBUCK  256    // power of two

// One block (256 threads) per row i. Each thread strides over j, accumulating
// wp[0..7] (row of W@P) and rs (row of W@1). d2 >= 30 terms are < 1e-13 and
// skipped on integer arithmetic alone (whole-wave execz skip for far chunks).
__global__ __launch_bounds__(256) void sncut_rows(const float* __restrict__ f,
                                                  const float* __restrict__ P,
                                                  float* __restrict__ buckets,
                                                  int bucket_mask)
{
    const int i   = blockIdx.x;
    const int tid = threadIdx.x;
    const int zi = i & 31, yi = (i >> 5) & 31, xi = i >> 10;
    const float fi = f[i];

    float wp0 = 0.f, wp1 = 0.f, wp2 = 0.f, wp3 = 0.f;
    float wp4 = 0.f, wp5 = 0.f, wp6 = 0.f, wp7 = 0.f;
    float rs  = 0.f;

    for (int j = tid; j < N; j += 256) {
        const int zj = j & 31, yj = (j >> 5) & 31, xj = j >> 10;
        const int dx = xi - xj, dy = yi - yj, dz = zi - zj;
        const int d2 = dx * dx + dy * dy + dz * dz;
        if (d2 < 30) {   // exp(-30) ~ 9e-14: negligible vs 2% threshold
            const float df  = fi - f[j];
            const float arg = df * df * (1.0f / 9.0f) + (float)d2;  // std_int=3, std_pos=1
            const float w   = __expf(-arg);
            const float4 p0 = *reinterpret_cast<const float4*>(P + (size_t)j * NCLS);
            const float4 p1 = *reinterpret_cast<const float4*>(P + (size_t)j * NCLS + 4);
            wp0 += w * p0.x; wp1 += w * p0.y; wp2 += w * p0.z; wp3 += w * p0.w;
            wp4 += w * p1.x; wp5 += w * p1.y; wp6 += w * p1.z; wp7 += w * p1.w;
            rs  += w;
        }
    }

    // ---- block reduction of 9 values: wave shuffle, then LDS across 4 waves
    float vals[9] = {wp0, wp1, wp2, wp3, wp4, wp5, wp6, wp7, rs};
    #pragma unroll
    for (int v = 0; v < 9; ++v) {
        float x = vals[v];
        #pragma unroll
        for (int off = 32; off > 0; off >>= 1)
            x += __shfl_down(x, off, 64);
        vals[v] = x;
    }

    __shared__ float part[4][9];
    __shared__ float totals[9];
    const int lane = tid & 63, wave = tid >> 6;
    if (lane == 0) {
        #pragma unroll
        for (int v = 0; v < 9; ++v) part[wave][v] = vals[v];
    }
    __syncthreads();
    if (tid < 9)
        totals[tid] = part[0][tid] + part[1][tid] + part[2][tid] + part[3][tid];
    __syncthreads();

    // ---- per-row contribution: num[t] += P[i,t]*WP[i,t]; den[t] += P[i,t]*rs
    if (tid < NCLS) {
        const float pit = P[(size_t)i * NCLS + tid];
        const int b = (i & bucket_mask) * 16;
        atomicAdd(&buckets[b + tid],        pit * totals[tid]);
        atomicAdd(&buckets[b + NCLS + tid], pit * totals[8]);
    }
}

__global__ __launch_bounds__(64) void sncut_final(const float* __restrict__ buckets,
                                                  int nbuckets,
                                                  float* __restrict__ out)
{
    __shared__ float sums[16];
    const int tid = threadIdx.x;
    if (tid < 16) {
        float s = 0.f;
        for (int b = 0; b < nbuckets; ++b) s += buckets[b * 16 + tid];
        sums[tid] = s;
    }
    __syncthreads();
    if (tid == 0) {
        float loss = (float)NCLS;
        #pragma unroll
        for (int t = 0; t < NCLS; ++t) loss -= sums[t] / sums[NCLS + t];
        out[0] = loss;
    }
}

extern "C" void kernel_launch(void* const* d_in, const int* in_sizes, int n_in,
                              void* d_out, int out_size, void* d_ws, size_t ws_size,
                              hipStream_t stream) {
    const float* f = (const float*)d_in[0];   // patch, 8192 fp32
    const float* P = (const float*)d_in[1];   // prob, 8192x8 fp32
    // d_in[2] is k==8 (compile-time constant here)

    // Defensive: shrink bucket count if ws is tiny (stays power of two).
    int nbuck = NBUCK;
    while ((size_t)nbuck * 16 * sizeof(float) > ws_size && nbuck > 1) nbuck >>= 1;

    float* buckets = (float*)d_ws;
    hipMemsetAsync(d_ws, 0, (size_t)nbuck * 16 * sizeof(float), stream);
    sncut_rows<<<N, 256, 0, stream>>>(f, P, buckets, nbuck - 1);
    sncut_final<<<1, 64, 0, stream>>>(buckets, nbuck, (float*)d_out);
}

// Round 2
// 85.271 us; speedup vs baseline: 1.5179x; 1.5179x over previous
//
#include <hip/hip_runtime.h>

#define N      8192   // 8*32*32  (DEPTH=8, LENGTH=32, WIDTH=32)
#define NCLS   8
#define NBUCK  256    // power of two

// One block (256 threads) per row i. Threads cover an 8(y) x 32(z) window
// around (yi, zi... z is full width), looping over xj in [xi-3, xi+3].
// All computed terms are EXACT; dropped terms have weight <= exp(-16) ~ 1e-7.
// Each thread accumulates wp[0..7] (row of W@P) and rs (row of W@1).
__global__ __launch_bounds__(256) void sncut_rows(const float* __restrict__ f,
                                                  const float* __restrict__ P,
                                                  float* __restrict__ buckets,
                                                  int bucket_mask)
{
    const int i   = blockIdx.x;
    const int tid = threadIdx.x;
    const int zi = i & 31, yi = (i >> 5) & 31, xi = i >> 10;
    const float fi = f[i];

    // Thread -> (yj, zj): 8 y-rows x 32 z-cols = 256 threads.
    const int zj = tid & 31;
    int y0 = yi - 3;
    y0 = y0 < 0 ? 0 : (y0 > 24 ? 24 : y0);       // window always inside [0,31]
    const int yj = y0 + (tid >> 5);

    const int dy = yi - yj, dz = zi - zj;
    const float base_d2 = (float)(dy * dy + dz * dz);

    int x0 = xi - 3; if (x0 < 0) x0 = 0;
    int x1 = xi + 3; if (x1 > 7) x1 = 7;

    float wp0 = 0.f, wp1 = 0.f, wp2 = 0.f, wp3 = 0.f;
    float wp4 = 0.f, wp5 = 0.f, wp6 = 0.f, wp7 = 0.f;
    float rs  = 0.f;

    const int jbase = (yj << 5) + zj;
    for (int xj = x0; xj <= x1; ++xj) {
        const int dx = xi - xj;
        const int j  = (xj << 10) + jbase;
        const float df  = fi - f[j];
        const float arg = df * df * (1.0f / 9.0f) + base_d2 + (float)(dx * dx);
        const float w   = __expf(-arg);
        const float4 p0 = *reinterpret_cast<const float4*>(P + (size_t)j * NCLS);
        const float4 p1 = *reinterpret_cast<const float4*>(P + (size_t)j * NCLS + 4);
        wp0 += w * p0.x; wp1 += w * p0.y; wp2 += w * p0.z; wp3 += w * p0.w;
        wp4 += w * p1.x; wp5 += w * p1.y; wp6 += w * p1.z; wp7 += w * p1.w;
        rs  += w;
    }

    // ---- block reduction of 9 values: wave shuffle, then LDS across 4 waves
    float vals[9] = {wp0, wp1, wp2, wp3, wp4, wp5, wp6, wp7, rs};
    #pragma unroll
    for (int v = 0; v < 9; ++v) {
        float x = vals[v];
        #pragma unroll
        for (int off = 32; off > 0; off >>= 1)
            x += __shfl_down(x, off, 64);
        vals[v] = x;
    }

    __shared__ float part[4][9];
    __shared__ float totals[9];
    const int lane = tid & 63, wave = tid >> 6;
    if (lane == 0) {
        #pragma unroll
        for (int v = 0; v < 9; ++v) part[wave][v] = vals[v];
    }
    __syncthreads();
    if (tid < 9)
        totals[tid] = part[0][tid] + part[1][tid] + part[2][tid] + part[3][tid];
    __syncthreads();

    // per-row contribution: num[t] += P[i,t]*WP[i,t]; den[t] += P[i,t]*rs
    if (tid < NCLS) {
        const float pit = P[(size_t)i * NCLS + tid];
        const int b = (i & bucket_mask) * 16;
        atomicAdd(&buckets[b + tid],        pit * totals[tid]);
        atomicAdd(&buckets[b + NCLS + tid], pit * totals[8]);
    }
}

// Parallel bucket fold: thread (g = tid>>4, e = tid&15) sums buckets[b*16+e]
// for b in {g, g+16, ...} -> 16 independent loads per thread (latency hidden),
// then LDS combine across the 16 groups.
__global__ __launch_bounds__(256) void sncut_final(const float* __restrict__ buckets,
                                                   int nbuckets,
                                                   float* __restrict__ out)
{
    const int tid = threadIdx.x;
    const int e = tid & 15;      // entry 0..15
    const int g = tid >> 4;      // group 0..15

    float s = 0.f;
    for (int b = g; b < nbuckets; b += 16)
        s += buckets[b * 16 + e];

    __shared__ float acc[16][17];
    acc[g][e] = s;
    __syncthreads();

    __shared__ float sums[16];
    if (tid < 16) {
        float t = 0.f;
        #pragma unroll
        for (int g2 = 0; g2 < 16; ++g2) t += acc[g2][tid];
        sums[tid] = t;
    }
    __syncthreads();
    if (tid == 0) {
        float loss = (float)NCLS;
        #pragma unroll
        for (int t = 0; t < NCLS; ++t) loss -= sums[t] / sums[NCLS + t];
        out[0] = loss;
    }
}

extern "C" void kernel_launch(void* const* d_in, const int* in_sizes, int n_in,
                              void* d_out, int out_size, void* d_ws, size_t ws_size,
                              hipStream_t stream) {
    const float* f = (const float*)d_in[0];   // patch, 8192 fp32
    const float* P = (const float*)d_in[1];   // prob, 8192x8 fp32
    // d_in[2] is k==8 (compile-time constant here)

    int nbuck = NBUCK;
    while ((size_t)nbuck * 16 * sizeof(float) > ws_size && nbuck > 1) nbuck >>= 1;

    float* buckets = (float*)d_ws;
    hipMemsetAsync(d_ws, 0, (size_t)nbuck * 16 * sizeof(float), stream);
    sncut_rows<<<N, 256, 0, stream>>>(f, P, buckets, nbuck - 1);
    sncut_final<<<1, 256, 0, stream>>>(buckets, nbuck, (float*)d_out);
}